// Round 10
// baseline (2588.714 us; speedup 1.0000x reference)
//
#include <hip/hip_runtime.h>
#include <cstdint>
#include <cstddef>

#define M_TOK 8192
#define DIMM  512
#define HEADS 8
#define DH    64
#define MLPD  2048
#define DEPTH 6

typedef unsigned short u16;
typedef unsigned int   u32;
typedef __attribute__((ext_vector_type(8))) short short8;   // 8 bf16 (4 VGPRs)
typedef __attribute__((ext_vector_type(4))) float f32x4;    // 4 fp32 acc

__device__ __forceinline__ float bf2f(u16 u){ return __uint_as_float(((u32)u) << 16); }
__device__ __forceinline__ u16 f2bf(float f){
    u32 x = __float_as_uint(f);
    u32 r = x + 0x7fffu + ((x >> 16) & 1u);   // RNE
    return (u16)(r >> 16);
}
__device__ __forceinline__ u16 f2bf_t(float f){ return (u16)(__float_as_uint(f) >> 16); }  // trunc

// ---------------- weight transpose + cvt: fp32 in[R][C] -> bf16 out[C][R], z layers ----------------
__global__ void k_transpose_cvt(const float* __restrict__ in, u16* __restrict__ out, int R, int C){
    __shared__ u16 tile[32][33];
    size_t zoff = (size_t)blockIdx.z * R * C;
    in += zoff; out += zoff;
    int c0 = blockIdx.x * 32, r0 = blockIdx.y * 32;
    int tx = threadIdx.x, ty = threadIdx.y;           // (32, 8)
    #pragma unroll
    for (int i = 0; i < 32; i += 8)
        tile[ty + i][tx] = f2bf(in[(size_t)(r0 + ty + i) * C + c0 + tx]);
    __syncthreads();
    #pragma unroll
    for (int i = 0; i < 32; i += 8)
        out[(size_t)(c0 + ty + i) * R + r0 + tx] = tile[tx][ty + i];
}

// ---------------- LayerNorm: fp32 x row -> bf16 out (fp32 scale/bias) ----------------
__global__ __launch_bounds__(64) void k_layernorm(const float* __restrict__ x,
                                                  const float* __restrict__ s,
                                                  const float* __restrict__ b,
                                                  u16* __restrict__ out){
    int row = blockIdx.x;
    int lane = threadIdx.x;
    const float* xp = x + (size_t)row * DIMM + lane * 8;
    float v[8];
    #pragma unroll
    for (int c = 0; c < 8; c++) v[c] = xp[c];
    float sum = 0.f, sq = 0.f;
    #pragma unroll
    for (int c = 0; c < 8; c++){ sum += v[c]; sq += v[c] * v[c]; }
    #pragma unroll
    for (int m = 32; m >= 1; m >>= 1){
        sum += __shfl_xor(sum, m);
        sq  += __shfl_xor(sq,  m);
    }
    float mu  = sum * (1.f / DIMM);
    float var = sq * (1.f / DIMM) - mu * mu;
    float rs  = rsqrtf(var + 1e-5f);
    u16* op = out + (size_t)row * DIMM + lane * 8;
    #pragma unroll
    for (int c = 0; c < 8; c++){
        int col = lane * 8 + c;
        op[c] = f2bf((v[c] - mu) * rs * s[col] + b[col]);
    }
}

__device__ __forceinline__ float gelu_exact(float v){
    return 0.5f * v * (1.f + erff(v * 0.70710678118654752f));
}

#define LDT64 72   // 64 k-elems + 8 pad; 144 B rows, 16B-aligned

// ---------------- 128x128-tile GEMM, BK=64, cross-iter prefetch, coalesced LDS epilogue ----------------
// Grid: x = m-tile (A-reuse clustered per XCD), y = n-tile.
// MODE 0: Cout=bf16(acc); MODE 1: Cout=bf16(gelu(acc+bias)).
template<int MODE>
__global__ __launch_bounds__(256) void k_gemm128b(const u16* __restrict__ A,
                                                  const u16* __restrict__ Bt,
                                                  const float* __restrict__ bias,
                                                  u16* __restrict__ Cout,
                                                  int M, int N, int K){
    __shared__ u16 As[128 * LDT64];
    __shared__ u16 Bs[128 * LDT64];
    int m0 = blockIdx.x * 128, n0 = blockIdx.y * 128;
    int t = threadIdx.x;
    int w = t >> 6, lane = t & 63;
    int mi = lane & 15, quad = lane >> 4;
    int wr = w >> 1, wc = w & 1;
    int srow = t >> 1, scol = (t & 1) * 32;          // 128 rows x 64 k / 256 thr

    const u16* ag = A  + (size_t)(m0 + srow) * K + scol;
    const u16* bg = Bt + (size_t)(n0 + srow) * K + scol;

    f32x4 acc[4][4];
    #pragma unroll
    for (int mt = 0; mt < 4; mt++)
        #pragma unroll
        for (int nt = 0; nt < 4; nt++) acc[mt][nt] = (f32x4){0.f, 0.f, 0.f, 0.f};

    uint4 pa[4], pb[4];
    #pragma unroll
    for (int j = 0; j < 4; j++){
        pa[j] = *(const uint4*)(ag + j * 8);
        pb[j] = *(const uint4*)(bg + j * 8);
    }

    for (int k0 = 0; k0 < K; k0 += 64){
        __syncthreads();   // previous iteration's ds_reads done
        #pragma unroll
        for (int j = 0; j < 4; j++){
            *(uint4*)&As[srow * LDT64 + scol + j * 8] = pa[j];
            *(uint4*)&Bs[srow * LDT64 + scol + j * 8] = pb[j];
        }
        // prefetch next tile NOW: in flight across barrier + MFMA section
        int kn = (k0 + 64 < K) ? (k0 + 64) : 0;
        #pragma unroll
        for (int j = 0; j < 4; j++){
            pa[j] = *(const uint4*)(ag + kn + j * 8);
            pb[j] = *(const uint4*)(bg + kn + j * 8);
        }
        __syncthreads();
        #pragma unroll
        for (int kk = 0; kk < 64; kk += 32){
            short8 af[4], bf[4];
            #pragma unroll
            for (int mt = 0; mt < 4; mt++)
                af[mt] = *(const short8*)&As[(wr * 64 + mt * 16 + mi) * LDT64 + kk + quad * 8];
            #pragma unroll
            for (int nt = 0; nt < 4; nt++)
                bf[nt] = *(const short8*)&Bs[(wc * 64 + nt * 16 + mi) * LDT64 + kk + quad * 8];
            #pragma unroll
            for (int mt = 0; mt < 4; mt++)
                #pragma unroll
                for (int nt = 0; nt < 4; nt++)
                    acc[mt][nt] = __builtin_amdgcn_mfma_f32_16x16x32_bf16(af[mt], bf[nt], acc[mt][nt], 0, 0, 0);
        }
    }

    // ---- coalesced epilogue: per-wave C-subtile through LDS ----
    float bv[4];
    if (MODE == 1){
        #pragma unroll
        for (int nt = 0; nt < 4; nt++) bv[nt] = bias[n0 + wc * 64 + nt * 16 + mi];
    }
    __syncthreads();
    u16* cs = &As[w * 16 * LDT64];
    int erow = lane >> 2, ecol = (lane & 3) * 16;
    #pragma unroll
    for (int mt = 0; mt < 4; mt++){
        #pragma unroll
        for (int nt = 0; nt < 4; nt++)
            #pragma unroll
            for (int r = 0; r < 4; r++){
                float v = acc[mt][nt][r];
                if (MODE == 1) v = gelu_exact(v + bv[nt]);
                cs[(quad * 4 + r) * LDT64 + nt * 16 + mi] = f2bf(v);
            }
        uint4 c0 = *(const uint4*)&cs[erow * LDT64 + ecol];
        uint4 c1 = *(const uint4*)&cs[erow * LDT64 + ecol + 8];
        u16* cp = Cout + (size_t)(m0 + wr * 64 + mt * 16 + erow) * N + n0 + wc * 64 + ecol;
        *(uint4*)cp       = c0;
        *(uint4*)(cp + 8) = c1;
    }
}

// ---------------- 64x64-tile GEMM, BK=64, cross-iter prefetch, fp32 residual RMW ----------------
// Grid: x = m-tile, y = n-tile.
__global__ __launch_bounds__(256) void k_gemm64_res(const u16* __restrict__ A,
                                                    const u16* __restrict__ Bt,
                                                    const float* __restrict__ bias,
                                                    float* __restrict__ xres,
                                                    int M, int N, int K){
    __shared__ u16 As[64 * LDT64];
    __shared__ u16 Bs[64 * LDT64];
    int m0 = blockIdx.x * 64, n0 = blockIdx.y * 64;
    int t = threadIdx.x;
    int w = t >> 6, lane = t & 63;
    int mi = lane & 15, quad = lane >> 4;
    int srow = t >> 2, scol = (t & 3) * 16;          // 64 rows x 64 k / 256 thr

    const u16* ag = A  + (size_t)(m0 + srow) * K + scol;
    const u16* bg = Bt + (size_t)(n0 + srow) * K + scol;

    f32x4 acc[4];
    #pragma unroll
    for (int tt = 0; tt < 4; tt++) acc[tt] = (f32x4){0.f, 0.f, 0.f, 0.f};

    uint4 pa[2], pb[2];
    pa[0] = *(const uint4*)(ag);     pa[1] = *(const uint4*)(ag + 8);
    pb[0] = *(const uint4*)(bg);     pb[1] = *(const uint4*)(bg + 8);

    for (int k0 = 0; k0 < K; k0 += 64){
        __syncthreads();
        *(uint4*)&As[srow * LDT64 + scol]     = pa[0];
        *(uint4*)&As[srow * LDT64 + scol + 8] = pa[1];
        *(uint4*)&Bs[srow * LDT64 + scol]     = pb[0];
        *(uint4*)&Bs[srow * LDT64 + scol + 8] = pb[1];
        int kn = (k0 + 64 < K) ? (k0 + 64) : 0;
        pa[0] = *(const uint4*)(ag + kn);     pa[1] = *(const uint4*)(ag + kn + 8);
        pb[0] = *(const uint4*)(bg + kn);     pb[1] = *(const uint4*)(bg + kn + 8);
        __syncthreads();
        short8 af0 = *(const short8*)&As[(w * 16 + mi) * LDT64 + quad * 8];
        short8 af1 = *(const short8*)&As[(w * 16 + mi) * LDT64 + quad * 8 + 32];
        #pragma unroll
        for (int tt = 0; tt < 4; tt++){
            short8 bf0 = *(const short8*)&Bs[(tt * 16 + mi) * LDT64 + quad * 8];
            short8 bf1 = *(const short8*)&Bs[(tt * 16 + mi) * LDT64 + quad * 8 + 32];
            acc[tt] = __builtin_amdgcn_mfma_f32_16x16x32_bf16(af0, bf0, acc[tt], 0, 0, 0);
            acc[tt] = __builtin_amdgcn_mfma_f32_16x16x32_bf16(af1, bf1, acc[tt], 0, 0, 0);
        }
    }

    // ---- coalesced fp32 RMW epilogue through LDS ----
    float bv[4];
    #pragma unroll
    for (int tt = 0; tt < 4; tt++) bv[tt] = bias[n0 + tt * 16 + mi];
    __syncthreads();
    float* cs = (w < 2) ? ((float*)As + w * 16 * LDT64)
                        : ((float*)Bs + (w - 2) * 16 * LDT64);
    #pragma unroll
    for (int tt = 0; tt < 4; tt++)
        #pragma unroll
        for (int r = 0; r < 4; r++)
            cs[(quad * 4 + r) * LDT64 + tt * 16 + mi] = acc[tt][r] + bv[tt];
    int erow = lane >> 2, ecol = (lane & 3) * 16;
    float* xp = xres + (size_t)(m0 + w * 16 + erow) * N + n0 + ecol;
    #pragma unroll
    for (int j = 0; j < 4; j++){
        float4 cv = *(const float4*)&cs[erow * LDT64 + ecol + j * 4];
        float4 xv = *(const float4*)(xp + j * 4);
        xv.x += cv.x; xv.y += cv.y; xv.z += cv.z; xv.w += cv.w;
        *(float4*)(xp + j * 4) = xv;
    }
}

// ---------------- MFMA flash attention: fixed-max softmax, l via ones-MFMA, 2 q-tiles/wave ----------------
// Grid: x = b*8+h (K/V-reuse clustered per XCD), y = q-tile (128 rows).
#define LDK 72
#define C1_LOG2E 0.18033688011112042f   // 0.125 * log2(e)
#define C2_LOG2E 11.541560327111707f    // 8 * log2(e)

__global__ __launch_bounds__(256) void k_flash(const u16* __restrict__ qkv, u16* __restrict__ out){
    __shared__ u16 Ks[64 * LDK];        // [key][dim]
    __shared__ u16 Vt[80 * LDK];        // [dim][key]; rows 64..79 = 1.0 (l-accumulator)
    __shared__ u16 Ps[4][32 * LDK];     // per-wave P [q32][key]
    int bh = blockIdx.x, qt = blockIdx.y;
    int b = bh >> 3, h = bh & 7;
    int t = threadIdx.x;
    int w = t >> 6, lane = t & 63;
    int mi = lane & 15, quad = lane >> 4;

    for (int i = t; i < 16 * 64; i += 256){
        int d = i >> 6, kk = i & 63;
        Vt[(64 + d) * LDK + kk] = 0x3F80;   // bf16 1.0
    }

    const u16* base = qkv + ((size_t)b * 1024) * 1536;
    int hoff = h * 64;

    short8 qf[2][2];
    #pragma unroll
    for (int qh = 0; qh < 2; qh++){
        int qrow = qt * 128 + w * 32 + qh * 16 + mi;
        const u16* qp = base + (size_t)qrow * 1536 + hoff + quad * 8;
        qf[qh][0] = *(const short8*)(qp);
        qf[qh][1] = *(const short8*)(qp + 32);
    }

    f32x4 o[2][4];
    f32x4 lacc[2];
    #pragma unroll
    for (int qh = 0; qh < 2; qh++){
        #pragma unroll
        for (int nb = 0; nb < 4; nb++) o[qh][nb] = (f32x4){0.f, 0.f, 0.f, 0.f};
        lacc[qh] = (f32x4){0.f, 0.f, 0.f, 0.f};
    }

    int kkey = t >> 2, kseg = t & 3;
    const u16* kgp = base + (size_t)kkey * 1536 + 512 + hoff + kseg * 16;
    int vkey = lane, vdg = w;
    const u16* vgp = base + (size_t)vkey * 1536 + 1024 + hoff + vdg * 16;

    for (int kt = 0; kt < 16; kt++){
        size_t koff = (size_t)kt * 64 * 1536;
        uint4 kv0 = *(const uint4*)(kgp + koff);
        uint4 kv1 = *(const uint4*)(kgp + koff + 8);
        uint4 vv0 = *(const uint4*)(vgp + koff);
        uint4 vv1 = *(const uint4*)(vgp + koff + 8);
        __syncthreads();
        *(uint4*)&Ks[kkey * LDK + kseg * 16]     = kv0;
        *(uint4*)&Ks[kkey * LDK + kseg * 16 + 8] = kv1;
        u16 vtmp[16];
        *(uint4*)&vtmp[0] = vv0;
        *(uint4*)&vtmp[8] = vv1;
        #pragma unroll
        for (int i = 0; i < 16; i++)
            Vt[(vdg * 16 + i) * LDK + vkey] = vtmp[i];   // 2 lanes/bank = free
        __syncthreads();

        short8 kb[4][2];
        #pragma unroll
        for (int nb = 0; nb < 4; nb++){
            kb[nb][0] = *(const short8*)&Ks[(nb * 16 + mi) * LDK + quad * 8];
            kb[nb][1] = *(const short8*)&Ks[(nb * 16 + mi) * LDK + quad * 8 + 32];
        }
        #pragma unroll
        for (int qh = 0; qh < 2; qh++){
            #pragma unroll
            for (int nb = 0; nb < 4; nb++){
                f32x4 z = (f32x4){0.f, 0.f, 0.f, 0.f};
                z = __builtin_amdgcn_mfma_f32_16x16x32_bf16(qf[qh][0], kb[nb][0], z, 0, 0, 0);
                z = __builtin_amdgcn_mfma_f32_16x16x32_bf16(qf[qh][1], kb[nb][1], z, 0, 0, 0);
                #pragma unroll
                for (int r = 0; r < 4; r++)
                    Ps[w][(qh * 16 + quad * 4 + r) * LDK + nb * 16 + mi] =
                        f2bf_t(exp2f(fmaf(z[r], C1_LOG2E, -C2_LOG2E)));
            }
        }
        short8 vb[4][2], lb[2];
        #pragma unroll
        for (int nb = 0; nb < 4; nb++){
            vb[nb][0] = *(const short8*)&Vt[(nb * 16 + mi) * LDK + quad * 8];
            vb[nb][1] = *(const short8*)&Vt[(nb * 16 + mi) * LDK + quad * 8 + 32];
        }
        lb[0] = *(const short8*)&Vt[(64 + mi) * LDK + quad * 8];
        lb[1] = *(const short8*)&Vt[(64 + mi) * LDK + quad * 8 + 32];
        #pragma unroll
        for (int qh = 0; qh < 2; qh++){
            const short8 a0 = *(const short8*)&Ps[w][(qh * 16 + mi) * LDK + quad * 8];
            const short8 a1 = *(const short8*)&Ps[w][(qh * 16 + mi) * LDK + quad * 8 + 32];
            #pragma unroll
            for (int nb = 0; nb < 4; nb++){
                o[qh][nb] = __builtin_amdgcn_mfma_f32_16x16x32_bf16(a0, vb[nb][0], o[qh][nb], 0, 0, 0);
                o[qh][nb] = __builtin_amdgcn_mfma_f32_16x16x32_bf16(a1, vb[nb][1], o[qh][nb], 0, 0, 0);
            }
            lacc[qh] = __builtin_amdgcn_mfma_f32_16x16x32_bf16(a0, lb[0], lacc[qh], 0, 0, 0);
            lacc[qh] = __builtin_amdgcn_mfma_f32_16x16x32_bf16(a1, lb[1], lacc[qh], 0, 0, 0);
        }
    }
    #pragma unroll
    for (int qh = 0; qh < 2; qh++){
        float invl[4];
        #pragma unroll
        for (int r = 0; r < 4; r++) invl[r] = 1.f / lacc[qh][r];
        u16* op = out + ((size_t)b * 1024 + qt * 128 + w * 32 + qh * 16) * 512 + hoff;
        #pragma unroll
        for (int nb = 0; nb < 4; nb++)
            #pragma unroll
            for (int r = 0; r < 4; r++)
                op[(quad * 4 + r) * 512 + nb * 16 + mi] = f2bf(o[qh][nb][r] * invl[r]);
    }
}

// ---------------- host launch ----------------
extern "C" void kernel_launch(void* const* d_in, const int* in_sizes, int n_in,
                              void* d_out, int out_size, void* d_ws, size_t ws_size,
                              hipStream_t stream){
    const float* x_in  = (const float*)d_in[0];
    const float* ln1_s = (const float*)d_in[1];
    const float* ln1_b = (const float*)d_in[2];
    const float* w_qkv = (const float*)d_in[3];
    const float* w_out = (const float*)d_in[4];
    const float* b_out = (const float*)d_in[5];
    const float* ln2_s = (const float*)d_in[6];
    const float* ln2_b = (const float*)d_in[7];
    const float* w1    = (const float*)d_in[8];
    const float* b1    = (const float*)d_in[9];
    const float* w2    = (const float*)d_in[10];
    const float* b2    = (const float*)d_in[11];
    float* out = (float*)d_out;

    char* ws = (char*)d_ws;
    float* x_f32 = (float*)ws;   ws += (size_t)M_TOK * DIMM * 4;      // 16 MB fp32 residual
    u16* bufA    = (u16*)ws;     ws += (size_t)M_TOK * DIMM * 2;      // 8 MB  (ln_out / attn_out)
    u16* bufB    = (u16*)ws;     ws += (size_t)M_TOK * MLPD * 2;      // 32 MB (qkv / mlp_h)
    u16* wbase   = (u16*)ws;
    size_t per_layer_w = (size_t)(1536 + 512 + 2048 + 2048) * 512;    // 6 MB

    size_t used_big = (size_t)(ws - (char*)d_ws) + per_layer_w * 2 * DEPTH;
    bool big = (ws_size >= used_big);

    u16* ln_out   = bufA;
    u16* attn_out = bufA;
    u16* qkv      = bufB;
    u16* mlp_h    = bufB;

    size_t x_bytes = (size_t)M_TOK * DIMM * sizeof(float);
    hipMemcpyAsync(x_f32, x_in, x_bytes, hipMemcpyDeviceToDevice, stream);

    const size_t off_qkv = 0;
    const size_t off_out = (size_t)1536 * 512;
    const size_t off_w1  = off_out + (size_t)512 * 512;
    const size_t off_w2  = off_w1 + (size_t)2048 * 512;

    if (big){
        k_transpose_cvt<<<dim3(48, 16, 6), dim3(32, 8), 0, stream>>>(w_qkv, wbase + off_qkv * DEPTH, 512, 1536);
        k_transpose_cvt<<<dim3(16, 16, 6), dim3(32, 8), 0, stream>>>(w_out, wbase + off_out * DEPTH, 512, 512);
        k_transpose_cvt<<<dim3(64, 16, 6), dim3(32, 8), 0, stream>>>(w1,    wbase + off_w1  * DEPTH, 512, 2048);
        k_transpose_cvt<<<dim3(16, 64, 6), dim3(32, 8), 0, stream>>>(w2,    wbase + off_w2  * DEPTH, 2048, 512);
    }

    for (int i = 0; i < DEPTH; i++){
        u16 *wqkvT, *woutT, *w1T, *w2T;
        if (big){
            wqkvT = wbase + off_qkv * DEPTH + (size_t)i * 1536 * 512;
            woutT = wbase + off_out * DEPTH + (size_t)i * 512 * 512;
            w1T   = wbase + off_w1  * DEPTH + (size_t)i * 2048 * 512;
            w2T   = wbase + off_w2  * DEPTH + (size_t)i * 512 * 2048;
        } else {
            wqkvT = wbase + off_qkv; woutT = wbase + off_out;
            w1T   = wbase + off_w1;  w2T   = wbase + off_w2;
            k_transpose_cvt<<<dim3(48, 16), dim3(32, 8), 0, stream>>>(w_qkv + (size_t)i * 512 * 1536, wqkvT, 512, 1536);
            k_transpose_cvt<<<dim3(16, 16), dim3(32, 8), 0, stream>>>(w_out + (size_t)i * 512 * 512,  woutT, 512, 512);
            k_transpose_cvt<<<dim3(64, 16), dim3(32, 8), 0, stream>>>(w1    + (size_t)i * 512 * 2048, w1T,   512, 2048);
            k_transpose_cvt<<<dim3(16, 64), dim3(32, 8), 0, stream>>>(w2    + (size_t)i * 2048 * 512, w2T,   2048, 512);
        }

        k_layernorm<<<dim3(M_TOK), dim3(64), 0, stream>>>(x_f32, ln1_s + i * 512, ln1_b + i * 512, ln_out);
        k_gemm128b<0><<<dim3(64, 12), dim3(256), 0, stream>>>(ln_out, wqkvT, nullptr, qkv,
                                                              M_TOK, 1536, 512);
        k_flash<<<dim3(64, 8), dim3(256), 0, stream>>>(qkv, attn_out);
        k_gemm64_res<<<dim3(128, 8), dim3(256), 0, stream>>>(attn_out, woutT, b_out + i * 512, x_f32,
                                                             M_TOK, 512, 512);
        k_layernorm<<<dim3(M_TOK), dim3(64), 0, stream>>>(x_f32, ln2_s + i * 512, ln2_b + i * 512, ln_out);
        k_gemm128b<1><<<dim3(64, 16), dim3(256), 0, stream>>>(ln_out, w1T, b1 + i * 2048, mlp_h,
                                                              M_TOK, 2048, 512);
        k_gemm64_res<<<dim3(128, 8), dim3(256), 0, stream>>>(mlp_h, w2T, b2 + i * 512, x_f32,
                                                             M_TOK, 512, 2048);
    }
    hipMemcpyAsync(out, x_f32, x_bytes, hipMemcpyDeviceToDevice, stream);
}